// Round 1
// baseline (143.371 us; speedup 1.0000x reference)
//
#include <hip/hip_runtime.h>

#define NBLOCKS 1024
#define NTHREADS 256

// piecewise_linear weight + 1.0, with compile-time a,b,c,d (mid = 1.0).
// Reference chain (t = -0.5 -> k = ln2/d, exp(-k(y-d)) = 2^(-(y-d)/d)):
//   [0,a): y/a ; [a,b]: 1 ; (b,c): 1-(y-b)/(c-b) ; [c,d]: 0 ; (d,inf): -1+2^(-(y-d)/d)
//   plus (pred<0 ? 1 : 0); final w_mid = 1 + w.
__device__ __forceinline__ float wmid(float yt, float yp,
                                      float a, float b, float c, float d) {
    float w;
    if (yt < 0.0f)       w = 0.0f;
    else if (yt < a)     w = yt * (1.0f / a);
    else if (yt <= b)    w = 1.0f;
    else if (yt < c)     w = 1.0f - (yt - b) * (1.0f / (c - b));
    else if (yt <= d)    w = 0.0f;
    else                 w = -1.0f + exp2f(-(yt - d) * (1.0f / d));
    if (yp < 0.0f) w += 1.0f;
    return 1.0f + w;
}

__device__ __forceinline__ float row_loss(float ph, float pd, float pn,
                                          float th, float td, float tn, int ot) {
    const float L2_11 = 0.13750352374993502f;  // log2(1.1)

    // head (HIC): thr {150,500,1000,1800,2600}
    int ap = (ph >= 150.0f) + (ph >= 500.0f) + (ph >= 1000.0f) + (ph >= 1800.0f) + (ph >= 2600.0f);
    int at = (th >= 150.0f) + (th >= 500.0f) + (th >= 1000.0f) + (th >= 1800.0f) + (th >= 2600.0f);
    float wc = exp2f(fabsf((float)(ap - at)) * L2_11);          // 1.1^|dais|
    float l  = fabsf(ph - th) * wc * wmid(th, ph, 80.0f, 1500.0f, 1750.0f, 2000.0f);

    // chest (Dmax): thr {22,35,45,55,65} * (0.8 + 0.1*ot)
    float s = 0.8f + 0.1f * (float)ot;
    ap = (pd >= 22.0f*s) + (pd >= 35.0f*s) + (pd >= 45.0f*s) + (pd >= 55.0f*s) + (pd >= 65.0f*s);
    at = (td >= 22.0f*s) + (td >= 35.0f*s) + (td >= 45.0f*s) + (td >= 55.0f*s) + (td >= 65.0f*s);
    wc = exp2f(fabsf((float)(ap - at)) * L2_11);
    l += fabsf(pd - td) * wc * wmid(td, pd, 10.0f, 75.0f, 85.0f, 100.0f);

    // neck (Nij): thr {0.2,0.5,1.0,1.5,2.0}
    ap = (pn >= 0.2f) + (pn >= 0.5f) + (pn >= 1.0f) + (pn >= 1.5f) + (pn >= 2.0f);
    at = (tn >= 0.2f) + (tn >= 0.5f) + (tn >= 1.0f) + (tn >= 1.5f) + (tn >= 2.0f);
    wc = exp2f(fabsf((float)(ap - at)) * L2_11);
    l += fabsf(pn - tn) * wc * wmid(tn, pn, 0.15f, 1.5f, 1.7f, 1.9f);

    return l;
}

__global__ __launch_bounds__(NTHREADS)
void weighted_loss_main(const float* __restrict__ pred,
                        const float* __restrict__ truth,
                        const int*   __restrict__ ot,
                        float* __restrict__ partial, int B) {
    const int nq     = B >> 2;                       // quads of 4 rows
    const int gid    = blockIdx.x * blockDim.x + threadIdx.x;
    const int stride = gridDim.x * blockDim.x;
    const float4* p4 = (const float4*)pred;
    const float4* t4 = (const float4*)truth;
    const int4*   o4 = (const int4*)ot;

    float acc = 0.0f;
    for (int q = gid; q < nq; q += stride) {
        float4 pa = p4[3*q + 0], pb = p4[3*q + 1], pc = p4[3*q + 2];
        float4 ta = t4[3*q + 0], tb = t4[3*q + 1], tc = t4[3*q + 2];
        int4   o  = o4[q];
        // rows: (h,d,n) packed 3-wide -> unpack 4 rows from 3 float4s
        float ph[4] = {pa.x, pa.w, pb.z, pc.y};
        float pD[4] = {pa.y, pb.x, pb.w, pc.z};
        float pn[4] = {pa.z, pb.y, pc.x, pc.w};
        float th[4] = {ta.x, ta.w, tb.z, tc.y};
        float tD[4] = {ta.y, tb.x, tb.w, tc.z};
        float tn[4] = {ta.z, tb.y, tc.x, tc.w};
        int   oo[4] = {o.x, o.y, o.z, o.w};
        #pragma unroll
        for (int j = 0; j < 4; ++j)
            acc += row_loss(ph[j], pD[j], pn[j], th[j], tD[j], tn[j], oo[j]);
    }
    // tail rows (B not multiple of 4) — none for B=4M, kept for generality
    for (int r = (nq << 2) + gid; r < B; r += stride)
        acc += row_loss(pred[3*r], pred[3*r+1], pred[3*r+2],
                        truth[3*r], truth[3*r+1], truth[3*r+2], ot[r]);

    // wave (64) reduce then cross-wave via LDS
    #pragma unroll
    for (int off = 32; off > 0; off >>= 1) acc += __shfl_down(acc, off, 64);
    __shared__ float sm[NTHREADS / 64];
    const int lane = threadIdx.x & 63, wid = threadIdx.x >> 6;
    if (lane == 0) sm[wid] = acc;
    __syncthreads();
    if (threadIdx.x == 0) {
        float s = 0.0f;
        #pragma unroll
        for (int w = 0; w < NTHREADS / 64; ++w) s += sm[w];
        partial[blockIdx.x] = s;
    }
}

__global__ __launch_bounds__(256)
void weighted_loss_reduce(const float* __restrict__ partial, int n,
                          float* __restrict__ out, float invB) {
    float acc = 0.0f;
    for (int i = threadIdx.x; i < n; i += blockDim.x) acc += partial[i];
    #pragma unroll
    for (int off = 32; off > 0; off >>= 1) acc += __shfl_down(acc, off, 64);
    __shared__ float sm[4];
    const int lane = threadIdx.x & 63, wid = threadIdx.x >> 6;
    if (lane == 0) sm[wid] = acc;
    __syncthreads();
    if (threadIdx.x == 0)
        out[0] = (sm[0] + sm[1] + sm[2] + sm[3]) * invB;
}

extern "C" void kernel_launch(void* const* d_in, const int* in_sizes, int n_in,
                              void* d_out, int out_size, void* d_ws, size_t ws_size,
                              hipStream_t stream) {
    const float* pred  = (const float*)d_in[0];   // (B,3) f32
    const float* truth = (const float*)d_in[1];   // (B,3) f32
    const int*   ot    = (const int*)d_in[2];     // (B,)  i32
    const int B = in_sizes[2];
    float* partial = (float*)d_ws;                // NBLOCKS floats, fully overwritten

    weighted_loss_main<<<NBLOCKS, NTHREADS, 0, stream>>>(pred, truth, ot, partial, B);
    weighted_loss_reduce<<<1, 256, 0, stream>>>(partial, NBLOCKS, (float*)d_out,
                                                1.0f / (float)B);
}

// Round 2
// 141.632 us; speedup vs baseline: 1.0123x; 1.0123x over previous
//
#include <hip/hip_runtime.h>

#define NTHREADS 256

// piecewise_linear weight + 1.0, with compile-time a,b,c,d (mid = 1.0).
// Reference chain (t = -0.5 -> k = ln2/d, exp(-k(y-d)) = 2^(-(y-d)/d)):
//   [0,a): y/a ; [a,b]: 1 ; (b,c): 1-(y-b)/(c-b) ; [c,d]: 0 ; (d,inf): -1+2^(-(y-d)/d)
//   plus (pred<0 ? 1 : 0); final w_mid = 1 + w.
__device__ __forceinline__ float wmid(float yt, float yp,
                                      float a, float b, float c, float d) {
    float w;
    if (yt < 0.0f)       w = 0.0f;
    else if (yt < a)     w = yt * (1.0f / a);
    else if (yt <= b)    w = 1.0f;
    else if (yt < c)     w = 1.0f - (yt - b) * (1.0f / (c - b));
    else if (yt <= d)    w = 0.0f;
    else                 w = -1.0f + exp2f(-(yt - d) * (1.0f / d));
    if (yp < 0.0f) w += 1.0f;
    return 1.0f + w;
}

__device__ __forceinline__ float row_loss(float ph, float pd, float pn,
                                          float th, float td, float tn, int ot) {
    const float L2_11 = 0.13750352374993502f;  // log2(1.1)

    // head (HIC): thr {150,500,1000,1800,2600}
    int ap = (ph >= 150.0f) + (ph >= 500.0f) + (ph >= 1000.0f) + (ph >= 1800.0f) + (ph >= 2600.0f);
    int at = (th >= 150.0f) + (th >= 500.0f) + (th >= 1000.0f) + (th >= 1800.0f) + (th >= 2600.0f);
    float wc = exp2f(fabsf((float)(ap - at)) * L2_11);          // 1.1^|dais|
    float l  = fabsf(ph - th) * wc * wmid(th, ph, 80.0f, 1500.0f, 1750.0f, 2000.0f);

    // chest (Dmax): thr {22,35,45,55,65} * (0.8 + 0.1*ot)
    float s = 0.8f + 0.1f * (float)ot;
    ap = (pd >= 22.0f*s) + (pd >= 35.0f*s) + (pd >= 45.0f*s) + (pd >= 55.0f*s) + (pd >= 65.0f*s);
    at = (td >= 22.0f*s) + (td >= 35.0f*s) + (td >= 45.0f*s) + (td >= 55.0f*s) + (td >= 65.0f*s);
    wc = exp2f(fabsf((float)(ap - at)) * L2_11);
    l += fabsf(pd - td) * wc * wmid(td, pd, 10.0f, 75.0f, 85.0f, 100.0f);

    // neck (Nij): thr {0.2,0.5,1.0,1.5,2.0}
    ap = (pn >= 0.2f) + (pn >= 0.5f) + (pn >= 1.0f) + (pn >= 1.5f) + (pn >= 2.0f);
    at = (tn >= 0.2f) + (tn >= 0.5f) + (tn >= 1.0f) + (tn >= 1.5f) + (tn >= 2.0f);
    wc = exp2f(fabsf((float)(ap - at)) * L2_11);
    l += fabsf(pn - tn) * wc * wmid(tn, pn, 0.15f, 1.5f, 1.7f, 1.9f);

    return l;
}

// One quad (4 rows = 3 float4s of pred/true + 1 int4 of ot) per thread.
// Grid sized so each thread does exactly one iteration -> max waves in
// flight, max outstanding loads (latency-bound fix for R1's 27% occupancy).
__global__ __launch_bounds__(NTHREADS)
void weighted_loss_main(const float* __restrict__ pred,
                        const float* __restrict__ truth,
                        const int*   __restrict__ ot,
                        float* __restrict__ partial, int B) {
    const int nq     = B >> 2;                       // quads of 4 rows
    const int gid    = blockIdx.x * blockDim.x + threadIdx.x;
    const int stride = gridDim.x * blockDim.x;
    const float4* p4 = (const float4*)pred;
    const float4* t4 = (const float4*)truth;
    const int4*   o4 = (const int4*)ot;

    float acc = 0.0f;
    for (int q = gid; q < nq; q += stride) {
        float4 pa = p4[3*q + 0], pb = p4[3*q + 1], pc = p4[3*q + 2];
        float4 ta = t4[3*q + 0], tb = t4[3*q + 1], tc = t4[3*q + 2];
        int4   o  = o4[q];
        // rows: (h,d,n) packed 3-wide -> unpack 4 rows from 3 float4s
        float ph[4] = {pa.x, pa.w, pb.z, pc.y};
        float pD[4] = {pa.y, pb.x, pb.w, pc.z};
        float pn[4] = {pa.z, pb.y, pc.x, pc.w};
        float th[4] = {ta.x, ta.w, tb.z, tc.y};
        float tD[4] = {ta.y, tb.x, tb.w, tc.z};
        float tn[4] = {ta.z, tb.y, tc.x, tc.w};
        int   oo[4] = {o.x, o.y, o.z, o.w};
        #pragma unroll
        for (int j = 0; j < 4; ++j)
            acc += row_loss(ph[j], pD[j], pn[j], th[j], tD[j], tn[j], oo[j]);
    }
    // tail rows (B not multiple of 4) — none for B=4M, kept for generality
    for (int r = (nq << 2) + gid; r < B; r += stride)
        acc += row_loss(pred[3*r], pred[3*r+1], pred[3*r+2],
                        truth[3*r], truth[3*r+1], truth[3*r+2], ot[r]);

    // wave (64) reduce then cross-wave via LDS
    #pragma unroll
    for (int off = 32; off > 0; off >>= 1) acc += __shfl_down(acc, off, 64);
    __shared__ float sm[NTHREADS / 64];
    const int lane = threadIdx.x & 63, wid = threadIdx.x >> 6;
    if (lane == 0) sm[wid] = acc;
    __syncthreads();
    if (threadIdx.x == 0) {
        float s = 0.0f;
        #pragma unroll
        for (int w = 0; w < NTHREADS / 64; ++w) s += sm[w];
        partial[blockIdx.x] = s;
    }
}

// Final reduce over per-block partials. n can be up to 16384.
__global__ __launch_bounds__(256)
void weighted_loss_reduce(const float* __restrict__ partial, int n,
                          float* __restrict__ out, float invB) {
    float acc = 0.0f;
    for (int i = threadIdx.x; i < n; i += blockDim.x) acc += partial[i];
    #pragma unroll
    for (int off = 32; off > 0; off >>= 1) acc += __shfl_down(acc, off, 64);
    __shared__ float sm[4];
    const int lane = threadIdx.x & 63, wid = threadIdx.x >> 6;
    if (lane == 0) sm[wid] = acc;
    __syncthreads();
    if (threadIdx.x == 0)
        out[0] = (sm[0] + sm[1] + sm[2] + sm[3]) * invB;
}

extern "C" void kernel_launch(void* const* d_in, const int* in_sizes, int n_in,
                              void* d_out, int out_size, void* d_ws, size_t ws_size,
                              hipStream_t stream) {
    const float* pred  = (const float*)d_in[0];   // (B,3) f32
    const float* truth = (const float*)d_in[1];   // (B,3) f32
    const int*   ot    = (const int*)d_in[2];     // (B,)  i32
    const int B = in_sizes[2];
    float* partial = (float*)d_ws;                // nblocks floats, fully overwritten

    const int nq = B >> 2;
    int nblocks = (nq + NTHREADS - 1) / NTHREADS;  // 1 quad per thread
    if (nblocks < 1) nblocks = 1;
    if (nblocks > 16384) nblocks = 16384;          // ws/partial safety cap

    weighted_loss_main<<<nblocks, NTHREADS, 0, stream>>>(pred, truth, ot, partial, B);
    weighted_loss_reduce<<<1, 256, 0, stream>>>(partial, nblocks, (float*)d_out,
                                                1.0f / (float)B);
}

// Round 3
// 138.401 us; speedup vs baseline: 1.0359x; 1.0233x over previous
//
#include <hip/hip_runtime.h>

#define NT 256
#define NB 1536   // NB*NT = 393216 threads; 393216 % 3 == 0 -> per-lane roles loop-invariant

// Branchless per-element loss. Constants are pre-selected per lane (hoisted).
// wmid is continuous at every segment boundary, so min/max composition is
// safe: ramp [0,a), plateau 1 [a,b], descend (b,c), zero [c,d], exp tail >d.
__device__ __forceinline__ float elem_loss(float p, float t, float se,
    float t0, float t1, float t2, float t3, float t4,
    float ainv, float bb, float cbinv, float dd, float dinv) {
    // scaled thresholds (se==1 for head/neck; matches ref's thr*scale order)
    float u0 = t0 * se, u1 = t1 * se, u2 = t2 * se, u3 = t3 * se, u4 = t4 * se;
    int ap = (p >= u0) + (p >= u1) + (p >= u2) + (p >= u3) + (p >= u4);
    int at = (t >= u0) + (t >= u1) + (t >= u2) + (t >= u3) + (t >= u4);
    float wc = exp2f(fabsf((float)(ap - at)) * 0.13750352374993502f); // 1.1^|d|
    float ramp = t * ainv;
    float down = 1.0f - (t - bb) * cbinv;
    float wm = fmaxf(fminf(fminf(ramp, 1.0f), down), 0.0f);  // covers t<0 .. d
    float tail = exp2f((dd - t) * dinv) - 1.0f;              // t>d: -1+2^(-(t-d)/d)
    wm = (t > dd) ? tail : wm;
    wm += (p < 0.0f) ? 2.0f : 1.0f;                          // +mid if pred<0, +1
    return fabsf(p - t) * wc * wm;
}

// Rotation-select: slot e has role (q+e)%3; pick from (head,chest,neck) values.
#define SEL0(x0, x1, x2) (c1 ? (x1) : (c2 ? (x2) : (x0)))
#define SEL1(x0, x1, x2) (c1 ? (x2) : (c2 ? (x0) : (x1)))
#define SEL2(x0, x1, x2) (c1 ? (x0) : (c2 ? (x1) : (x2)))

#define DECL_SLOT(n, SEL) \
    const float t0_##n = SEL(150.0f, 22.0f, 0.2f); \
    const float t1_##n = SEL(500.0f, 35.0f, 0.5f); \
    const float t2_##n = SEL(1000.0f, 45.0f, 1.0f); \
    const float t3_##n = SEL(1800.0f, 55.0f, 1.5f); \
    const float t4_##n = SEL(2600.0f, 65.0f, 2.0f); \
    const float ainv_##n = SEL(0.0125f, 0.1f, 6.6666667f); \
    const float bb_##n   = SEL(1500.0f, 75.0f, 1.5f); \
    const float cbinv_##n= SEL(0.004f, 0.1f, 5.0f); \
    const float dd_##n   = SEL(2000.0f, 100.0f, 1.9f); \
    const float dinv_##n = SEL(0.0005f, 0.01f, 0.52631579f); \
    const bool  ch_##n   = SEL(false, true, false);

#define SLOT_LOSS(n, p, t) \
    elem_loss((p), (t), ch_##n ? (off_##n ? s1 : s0) : 1.0f, \
              t0_##n, t1_##n, t2_##n, t3_##n, t4_##n, \
              ainv_##n, bb_##n, cbinv_##n, dd_##n, dinv_##n)

__global__ __launch_bounds__(NT)
void weighted_loss_main(const float* __restrict__ pred,
                        const float* __restrict__ truth,
                        const int*   __restrict__ ot,
                        float* __restrict__ partial, int B) {
    const int total  = 3 * B;                 // flat element count
    const int nchunk = total >> 2;            // float4 chunks
    const int g = blockIdx.x * NT + threadIdx.x;
    const int S = gridDim.x * NT;             // ≡ 0 (mod 3) by construction

    // q = chunk % 3, invariant across grid-stride iterations
    const int  q  = g % 3;
    const bool c1 = (q == 1), c2 = (q == 2);

    DECL_SLOT(a, SEL0)   // slot e=0 (and e=3: same role q)
    DECL_SLOT(b, SEL1)   // slot e=1, role (q+1)%3
    DECL_SLOT(c, SEL2)   // slot e=2, role (q+2)%3

    // slot row offsets: row(e) = r0 + (q+e)/3
    const bool off_a = false;
    const bool off_b = c2;
    const bool off_c = c1 || c2;
    const bool off_d = true;   // slot 3 (role q, consts _a)

    const float4* p4 = (const float4*)pred;
    const float4* t4 = (const float4*)truth;

    float acc = 0.0f;
    for (int C = g; C < nchunk; C += S) {
        float4 pv = p4[C];
        float4 tv = t4[C];
        // r0 = floor(4C/3) = (4C - q)/3, exact division via magic
        unsigned r0 = (unsigned)(((4u * (unsigned)C - (unsigned)q) * 0xAAAAAAABull) >> 33);
        int o0 = ot[r0];
        int o1 = ot[r0 + 1];
        float s0 = fmaf(0.1f, (float)o0, 0.8f);
        float s1 = fmaf(0.1f, (float)o1, 0.8f);

        acc += SLOT_LOSS(a, pv.x, tv.x);
        acc += SLOT_LOSS(b, pv.y, tv.y);
        acc += SLOT_LOSS(c, pv.z, tv.z);
        // slot 3: same role/constants as slot 0, row r0+1
        acc += elem_loss(pv.w, tv.w, ch_a ? (off_d ? s1 : s0) : 1.0f,
                         t0_a, t1_a, t2_a, t3_a, t4_a,
                         ainv_a, bb_a, cbinv_a, dd_a, dinv_a);
        (void)off_a;
    }

    // generic tail (elements beyond last full chunk); empty for B=4M
    for (int idx = (nchunk << 2) + g; idx < total; idx += S) {
        int role = idx % 3, row = idx / 3;
        float p = pred[idx], t = truth[idx];
        float l;
        if (role == 0)
            l = elem_loss(p, t, 1.0f, 150.0f, 500.0f, 1000.0f, 1800.0f, 2600.0f,
                          0.0125f, 1500.0f, 0.004f, 2000.0f, 0.0005f);
        else if (role == 1)
            l = elem_loss(p, t, fmaf(0.1f, (float)ot[row], 0.8f),
                          22.0f, 35.0f, 45.0f, 55.0f, 65.0f,
                          0.1f, 75.0f, 0.1f, 100.0f, 0.01f);
        else
            l = elem_loss(p, t, 1.0f, 0.2f, 0.5f, 1.0f, 1.5f, 2.0f,
                          6.6666667f, 1.5f, 5.0f, 1.9f, 0.52631579f);
        acc += l;
    }

    // wave (64) reduce then cross-wave via LDS
    #pragma unroll
    for (int off = 32; off > 0; off >>= 1) acc += __shfl_down(acc, off, 64);
    __shared__ float sm[NT / 64];
    const int lane = threadIdx.x & 63, wid = threadIdx.x >> 6;
    if (lane == 0) sm[wid] = acc;
    __syncthreads();
    if (threadIdx.x == 0) {
        float s = 0.0f;
        #pragma unroll
        for (int w = 0; w < NT / 64; ++w) s += sm[w];
        partial[blockIdx.x] = s;
    }
}

__global__ __launch_bounds__(256)
void weighted_loss_reduce(const float* __restrict__ partial, int n,
                          float* __restrict__ out, float invB) {
    float acc = 0.0f;
    for (int i = threadIdx.x; i < n; i += blockDim.x) acc += partial[i];
    #pragma unroll
    for (int off = 32; off > 0; off >>= 1) acc += __shfl_down(acc, off, 64);
    __shared__ float sm[4];
    const int lane = threadIdx.x & 63, wid = threadIdx.x >> 6;
    if (lane == 0) sm[wid] = acc;
    __syncthreads();
    if (threadIdx.x == 0)
        out[0] = (sm[0] + sm[1] + sm[2] + sm[3]) * invB;
}

extern "C" void kernel_launch(void* const* d_in, const int* in_sizes, int n_in,
                              void* d_out, int out_size, void* d_ws, size_t ws_size,
                              hipStream_t stream) {
    const float* pred  = (const float*)d_in[0];   // (B,3) f32
    const float* truth = (const float*)d_in[1];   // (B,3) f32
    const int*   ot    = (const int*)d_in[2];     // (B,)  i32
    const int B = in_sizes[2];
    float* partial = (float*)d_ws;                // NB floats, fully overwritten

    weighted_loss_main<<<NB, NT, 0, stream>>>(pred, truth, ot, partial, B);
    weighted_loss_reduce<<<1, 256, 0, stream>>>(partial, NB, (float*)d_out,
                                                1.0f / (float)B);
}

// Round 5
// 137.648 us; speedup vs baseline: 1.0416x; 1.0055x over previous
//
#include <hip/hip_runtime.h>

#define NT 256
#define NB 3072   // NB*NT = 786432 threads; %3==0 -> roles loop-invariant;
                  // 4*786432 = 3145728 = nchunk exactly for B=4M (no loop, U=4 MLP)

// Branchless per-element loss. Constants pre-selected per lane (hoisted).
// wmid is continuous at every boundary: ramp [0,a), 1 [a,b], down (b,c),
// 0 [c,d], exp tail >d; +1 if pred<0; final weight = 1 + w.
__device__ __forceinline__ float elem_loss(float p, float t, float se,
    float t0, float t1, float t2, float t3, float t4,
    float ainv, float bb, float cbinv, float dd, float dinv) {
    float u0 = t0 * se, u1 = t1 * se, u2 = t2 * se, u3 = t3 * se, u4 = t4 * se;
    int ap = (p >= u0) + (p >= u1) + (p >= u2) + (p >= u3) + (p >= u4);
    int at = (t >= u0) + (t >= u1) + (t >= u2) + (t >= u3) + (t >= u4);
    float wc = exp2f(fabsf((float)(ap - at)) * 0.13750352374993502f); // 1.1^|d|
    float ramp = t * ainv;
    float down = 1.0f - (t - bb) * cbinv;
    float wm = fmaxf(fminf(fminf(ramp, 1.0f), down), 0.0f);
    float tail = exp2f((dd - t) * dinv) - 1.0f;
    wm = (t > dd) ? tail : wm;
    wm += (p < 0.0f) ? 2.0f : 1.0f;
    return fabsf(p - t) * wc * wm;
}

// Rotation-select: slot e has role (q+e)%3; pick from (head,chest,neck).
#define SEL0(x0, x1, x2) (c1 ? (x1) : (c2 ? (x2) : (x0)))
#define SEL1(x0, x1, x2) (c1 ? (x2) : (c2 ? (x0) : (x1)))
#define SEL2(x0, x1, x2) (c1 ? (x0) : (c2 ? (x1) : (x2)))

#define DECL_SLOT(n, SEL) \
    const float t0_##n = SEL(150.0f, 22.0f, 0.2f); \
    const float t1_##n = SEL(500.0f, 35.0f, 0.5f); \
    const float t2_##n = SEL(1000.0f, 45.0f, 1.0f); \
    const float t3_##n = SEL(1800.0f, 55.0f, 1.5f); \
    const float t4_##n = SEL(2600.0f, 65.0f, 2.0f); \
    const float ainv_##n = SEL(0.0125f, 0.1f, 6.6666667f); \
    const float bb_##n   = SEL(1500.0f, 75.0f, 1.5f); \
    const float cbinv_##n= SEL(0.004f, 0.1f, 5.0f); \
    const float dd_##n   = SEL(2000.0f, 100.0f, 1.9f); \
    const float dinv_##n = SEL(0.0005f, 0.01f, 0.52631579f); \
    const bool  ch_##n   = SEL(false, true, false);

#define SLOT_LOSS(n, p, t, s0, s1) \
    elem_loss((p), (t), ch_##n ? (off_##n ? (s1) : (s0)) : 1.0f, \
              t0_##n, t1_##n, t2_##n, t3_##n, t4_##n, \
              ainv_##n, bb_##n, cbinv_##n, dd_##n, dinv_##n)

__global__ __launch_bounds__(NT)
void weighted_loss_main(const float* __restrict__ pred,
                        const float* __restrict__ truth,
                        const int*   __restrict__ ot,
                        float* __restrict__ partial, int B) {
    const int total  = 3 * B;
    const int nchunk = total >> 2;
    const int g = blockIdx.x * NT + threadIdx.x;
    const int S = gridDim.x * NT;            // ≡ 0 (mod 3)

    const int  q  = g % 3;                   // chunk role phase, loop-invariant
    const bool c1 = (q == 1), c2 = (q == 2);

    DECL_SLOT(a, SEL0)   // slot e=0 (and e=3), role q
    DECL_SLOT(b, SEL1)   // slot e=1, role (q+1)%3
    DECL_SLOT(c, SEL2)   // slot e=2, role (q+2)%3

    const bool off_a = false;  // slot 0: row r0
    const bool off_b = c2;
    const bool off_c = c1 || c2;

    const float4* p4 = (const float4*)pred;
    const float4* t4 = (const float4*)truth;

    float acc = 0.0f;

    if (nchunk == (S << 2)) {
        // Specialized path: exactly 4 chunks/thread. Batch-issue ALL loads
        // first (16 outstanding VMEM per lane = 4x MLP vs R3), then consume.
        float4 pv[4], tv[4];
        int    o0[4], o1[4];
        #pragma unroll
        for (int k = 0; k < 4; ++k) {
            const int C = g + k * S;
            pv[k] = p4[C];
            tv[k] = t4[C];
            unsigned r0 = (unsigned)(((4u * (unsigned)C - (unsigned)q)
                                      * 0xAAAAAAABull) >> 33);   // (4C-q)/3 exact
            o0[k] = ot[r0];
            o1[k] = ot[r0 + 1];
        }
        #pragma unroll
        for (int k = 0; k < 4; ++k) {
            float s0 = fmaf(0.1f, (float)o0[k], 0.8f);
            float s1 = fmaf(0.1f, (float)o1[k], 0.8f);
            acc += SLOT_LOSS(a, pv[k].x, tv[k].x, s0, s1);
            acc += SLOT_LOSS(b, pv[k].y, tv[k].y, s0, s1);
            acc += SLOT_LOSS(c, pv[k].z, tv[k].z, s0, s1);
            acc += elem_loss(pv[k].w, tv[k].w, ch_a ? s1 : 1.0f,  // slot3: role q, row r0+1
                             t0_a, t1_a, t2_a, t3_a, t4_a,
                             ainv_a, bb_a, cbinv_a, dd_a, dinv_a);
        }
    } else {
        // Generic fallback (any B): grid-stride, role still invariant.
        for (int C = g; C < nchunk; C += S) {
            float4 pv = p4[C];
            float4 tv = t4[C];
            unsigned r0 = (unsigned)(((4u * (unsigned)C - (unsigned)q)
                                      * 0xAAAAAAABull) >> 33);
            float s0 = fmaf(0.1f, (float)ot[r0], 0.8f);
            float s1 = fmaf(0.1f, (float)ot[r0 + 1], 0.8f);
            acc += SLOT_LOSS(a, pv.x, tv.x, s0, s1);
            acc += SLOT_LOSS(b, pv.y, tv.y, s0, s1);
            acc += SLOT_LOSS(c, pv.z, tv.z, s0, s1);
            acc += elem_loss(pv.w, tv.w, ch_a ? s1 : 1.0f,
                             t0_a, t1_a, t2_a, t3_a, t4_a,
                             ainv_a, bb_a, cbinv_a, dd_a, dinv_a);
        }
        // element tail (total not multiple of 4)
        for (int idx = (nchunk << 2) + g; idx < total; idx += S) {
            int role = idx % 3, row = idx / 3;
            float p = pred[idx], t = truth[idx];
            if (role == 0)
                acc += elem_loss(p, t, 1.0f, 150.0f, 500.0f, 1000.0f, 1800.0f, 2600.0f,
                                 0.0125f, 1500.0f, 0.004f, 2000.0f, 0.0005f);
            else if (role == 1)
                acc += elem_loss(p, t, fmaf(0.1f, (float)ot[row], 0.8f),
                                 22.0f, 35.0f, 45.0f, 55.0f, 65.0f,
                                 0.1f, 75.0f, 0.1f, 100.0f, 0.01f);
            else
                acc += elem_loss(p, t, 1.0f, 0.2f, 0.5f, 1.0f, 1.5f, 2.0f,
                                 6.6666667f, 1.5f, 5.0f, 1.9f, 0.52631579f);
        }
    }

    // wave (64) reduce then cross-wave via LDS
    #pragma unroll
    for (int off = 32; off > 0; off >>= 1) acc += __shfl_down(acc, off, 64);
    __shared__ float sm[NT / 64];
    const int lane = threadIdx.x & 63, wid = threadIdx.x >> 6;
    if (lane == 0) sm[wid] = acc;
    __syncthreads();
    if (threadIdx.x == 0) {
        float s = 0.0f;
        #pragma unroll
        for (int w = 0; w < NT / 64; ++w) s += sm[w];
        partial[blockIdx.x] = s;
    }
}

__global__ __launch_bounds__(1024)
void weighted_loss_reduce(const float* __restrict__ partial, int n,
                          float* __restrict__ out, float invB) {
    float acc = 0.0f;
    for (int i = threadIdx.x; i < n; i += blockDim.x) acc += partial[i];
    #pragma unroll
    for (int off = 32; off > 0; off >>= 1) acc += __shfl_down(acc, off, 64);
    __shared__ float sm[16];
    const int lane = threadIdx.x & 63, wid = threadIdx.x >> 6;
    if (lane == 0) sm[wid] = acc;
    __syncthreads();
    if (threadIdx.x == 0) {
        float s = 0.0f;
        #pragma unroll
        for (int w = 0; w < 16; ++w) s += sm[w];
        out[0] = s * invB;
    }
}

extern "C" void kernel_launch(void* const* d_in, const int* in_sizes, int n_in,
                              void* d_out, int out_size, void* d_ws, size_t ws_size,
                              hipStream_t stream) {
    const float* pred  = (const float*)d_in[0];   // (B,3) f32
    const float* truth = (const float*)d_in[1];   // (B,3) f32
    const int*   ot    = (const int*)d_in[2];     // (B,)  i32
    const int B = in_sizes[2];
    float* partial = (float*)d_ws;                // NB floats, fully overwritten

    weighted_loss_main<<<NB, NT, 0, stream>>>(pred, truth, ot, partial, B);
    weighted_loss_reduce<<<1, 1024, 0, stream>>>(partial, NB, (float*)d_out,
                                                 1.0f / (float)B);
}